// Round 1
// baseline (16881.465 us; speedup 1.0000x reference)
//
#include <hip/hip_runtime.h>

#define D 256
#define RREL 16
#define BB 8
#define EB 64
#define LN_EPS 1e-5f

// W[r,i,o] = sum_b att[r,b] * basis[b,i,o]
__global__ __launch_bounds__(256) void k_make_W(const float* __restrict__ att,
                                                const float* __restrict__ basis,
                                                float* __restrict__ W) {
    int idx = blockIdx.x * 256 + threadIdx.x;   // r*65536 + i*256 + o
    int r = idx >> 16;
    int io = idx & 65535;
    float acc = 0.f;
#pragma unroll
    for (int b = 0; b < BB; ++b) acc += att[r * BB + b] * basis[b * 65536 + io];
    W[idx] = acc;
}

__global__ void k_hist(const int* __restrict__ et, int* __restrict__ hist, int E) {
    int e = blockIdx.x * 256 + threadIdx.x;
    if (e < E) atomicAdd(&hist[et[e]], 1);
}

// single-thread exclusive scan with EB alignment; self-loops go in bucket R-1
__global__ void k_scan(const int* __restrict__ hist, int* __restrict__ start,
                       int* __restrict__ cursor, int N) {
    int s = 0;
    for (int r = 0; r < RREL; ++r) {
        start[r] = s;
        cursor[r] = s;
        int c = hist[r] + (r == RREL - 1 ? N : 0);
        s += ((c + EB - 1) / EB) * EB;
    }
    start[RREL] = s;
}

__global__ void k_cnt_init(float* __restrict__ cnt, int N) {
    int n = blockIdx.x * 256 + threadIdx.x;
    if (n < N) cnt[n] = 1.0f;   // self-loop contributes 1
}

__global__ void k_scatter(const int* __restrict__ ei, const int* __restrict__ et,
                          const float* __restrict__ ea, int* __restrict__ cursor,
                          int* __restrict__ ssrc, int* __restrict__ sdst,
                          int* __restrict__ stype, float* __restrict__ sea,
                          float* __restrict__ cnt, int E) {
    int e = blockIdx.x * 256 + threadIdx.x;
    if (e >= E) return;
    int r = et[e];
    int dst = ei[E + e];
    int p = atomicAdd(&cursor[r], 1);
    ssrc[p] = ei[e];
    sdst[p] = dst;
    stype[p] = r;
    sea[p] = ea[e];
    atomicAdd(&cnt[dst], 1.0f);
}

__global__ void k_self(int* __restrict__ cursor, int* __restrict__ ssrc,
                       int* __restrict__ sdst, int* __restrict__ stype,
                       float* __restrict__ sea, int N) {
    int n = blockIdx.x * 256 + threadIdx.x;
    if (n >= N) return;
    int p = atomicAdd(&cursor[RREL - 1], 1);
    ssrc[p] = n;
    sdst[p] = n;
    stype[p] = RREL - 1;
    sea[p] = 1.0f;
}

// One block = 64 edges of one relation. Gather x rows -> LDS, GEMM vs W[r],
// scale by ea, atomic scatter-add into agg[dst].
__global__ __launch_bounds__(256) void k_edge_gemm(
    const float* __restrict__ x, const float* __restrict__ W,
    const int* __restrict__ ssrc, const int* __restrict__ sdst,
    const int* __restrict__ stype, const float* __restrict__ sea,
    float* __restrict__ agg) {
    __shared__ float Xs[EB][D];   // 64 KB
    int base = blockIdx.x * EB;
    int tid = threadIdx.x;
    int r = stype[base];          // ranges are EB-aligned: whole block same relation

    // stage 64 gathered rows, coalesced float4 (wave handles one row per step)
#pragma unroll
    for (int j = 0; j < 16; ++j) {
        int e = j * 4 + (tid >> 6);
        int col = (tid & 63) * 4;
        int s = ssrc[base + e];
        *(float4*)&Xs[e][col] = *(const float4*)&x[(size_t)s * D + col];
    }
    __syncthreads();

    int og = tid & 31, eg = tid >> 5;
    int o0 = og * 8, e0 = eg * 8;
    const float* Wr = W + (size_t)r * D * D;

    float acc[8][8];
#pragma unroll
    for (int k = 0; k < 8; ++k)
#pragma unroll
        for (int j = 0; j < 8; ++j) acc[k][j] = 0.f;

    for (int i = 0; i < D; i += 4) {
        float xv[8][4];
#pragma unroll
        for (int k = 0; k < 8; ++k)
            *(float4*)xv[k] = *(const float4*)&Xs[e0 + k][i];
#pragma unroll
        for (int ii = 0; ii < 4; ++ii) {
            float wv[8];
            *(float4*)&wv[0] = *(const float4*)(Wr + (i + ii) * D + o0);
            *(float4*)&wv[4] = *(const float4*)(Wr + (i + ii) * D + o0 + 4);
#pragma unroll
            for (int k = 0; k < 8; ++k) {
                float xs = xv[k][ii];
#pragma unroll
                for (int j = 0; j < 8; ++j) acc[k][j] += xs * wv[j];
            }
        }
    }

#pragma unroll
    for (int k = 0; k < 8; ++k) {
        int e = base + e0 + k;
        float eav = sea[e];
        if (eav != 0.f) {   // padding entries have ea==0
            size_t dbase = (size_t)sdst[e] * D + o0;
#pragma unroll
            for (int j = 0; j < 8; ++j) atomicAdd(&agg[dbase + j], acc[k][j] * eav);
        }
    }
}

// h_out = agg/cnt + hin@root + bias ; hout = relu(LN(hin + h_out)) -- 8 rows/block
__global__ __launch_bounds__(256) void k_finish(
    const float* __restrict__ hin, const float* __restrict__ agg,
    const float* __restrict__ cnt, const float* __restrict__ root,
    const float* __restrict__ bias, const float* __restrict__ g,
    const float* __restrict__ bln, float* __restrict__ hout) {
    __shared__ float Xs[8][D];
    __shared__ float Rs[8][D];
    __shared__ float mv[8][2];
    int tid = threadIdx.x;
    int row0 = blockIdx.x * 8;

#pragma unroll
    for (int k = 0; k < 8; ++k) Xs[k][tid] = hin[(size_t)(row0 + k) * D + tid];
    __syncthreads();

    float accr[8];
#pragma unroll
    for (int k = 0; k < 8; ++k) accr[k] = 0.f;
    for (int i = 0; i < D; ++i) {
        float w = root[i * D + tid];
#pragma unroll
        for (int k = 0; k < 8; ++k) accr[k] += Xs[k][i] * w;
    }

    float bo = bias[tid];
#pragma unroll
    for (int k = 0; k < 8; ++k) {
        int n = row0 + k;
        float val = agg[(size_t)n * D + tid] / cnt[n] + accr[k] + bo;
        Rs[k][tid] = Xs[k][tid] + val;   // residual
    }
    __syncthreads();

    int wv = tid >> 6, lane = tid & 63;
#pragma unroll
    for (int rr = 0; rr < 2; ++rr) {
        int row = wv * 2 + rr;
        float s = 0.f, sq = 0.f;
#pragma unroll
        for (int j = 0; j < 4; ++j) {
            float v = Rs[row][lane + j * 64];
            s += v;
            sq += v * v;
        }
#pragma unroll
        for (int off = 32; off >= 1; off >>= 1) {
            s += __shfl_xor(s, off, 64);
            sq += __shfl_xor(sq, off, 64);
        }
        if (lane == 0) {
            float mu = s * (1.f / D);
            float var = sq * (1.f / D) - mu * mu;
            mv[row][0] = mu;
            mv[row][1] = rsqrtf(var + LN_EPS);
        }
    }
    __syncthreads();

    float gg = g[tid], bb = bln[tid];
#pragma unroll
    for (int k = 0; k < 8; ++k) {
        float o = (Rs[k][tid] - mv[k][0]) * mv[k][1] * gg + bb;
        hout[(size_t)(row0 + k) * D + tid] = fmaxf(o, 0.f);
    }
}

extern "C" void kernel_launch(void* const* d_in, const int* in_sizes, int n_in,
                              void* d_out, int out_size, void* d_ws, size_t ws_size,
                              hipStream_t stream) {
    const float* x      = (const float*)d_in[0];
    const int*   ei     = (const int*)d_in[1];
    const int*   et     = (const int*)d_in[2];
    const float* ea     = (const float*)d_in[3];
    const float* basis1 = (const float*)d_in[4];
    const float* att1   = (const float*)d_in[5];
    const float* root1  = (const float*)d_in[6];
    const float* bias1  = (const float*)d_in[7];
    const float* g1     = (const float*)d_in[8];
    const float* b1     = (const float*)d_in[9];
    const float* basis2 = (const float*)d_in[10];
    const float* att2   = (const float*)d_in[11];
    const float* root2  = (const float*)d_in[12];
    const float* bias2  = (const float*)d_in[13];
    const float* g2     = (const float*)d_in[14];
    const float* b2     = (const float*)d_in[15];
    float* out = (float*)d_out;

    int N = in_sizes[0] / D;
    int E = in_sizes[2];
    int cap = ((E + N + RREL * (EB - 1)) + EB - 1) / EB * EB;   // padded sorted size

    char* p = (char*)d_ws;
    auto alloc = [&](size_t bytes) {
        char* q = p;
        p += (bytes + 255) & ~(size_t)255;
        return q;
    };
    float* W     = (float*)alloc((size_t)RREL * D * D * 4);
    float* agg   = (float*)alloc((size_t)N * D * 4);
    float* cnt   = (float*)alloc((size_t)N * 4);
    int*   ssrc  = (int*)  alloc((size_t)cap * 4);
    int*   sdst  = (int*)  alloc((size_t)cap * 4);
    int*   stype = (int*)  alloc((size_t)cap * 4);
    float* seav  = (float*)alloc((size_t)cap * 4);
    int*   hist  = (int*)  alloc(RREL * 4);
    int*   start = (int*)  alloc((RREL + 1) * 4);
    int*   curs  = (int*)  alloc(RREL * 4);

    // zero init (ws is poisoned)
    hipMemsetAsync(hist, 0, RREL * 4, stream);
    hipMemsetAsync(ssrc, 0, (size_t)cap * 4, stream);
    hipMemsetAsync(sdst, 0, (size_t)cap * 4, stream);
    hipMemsetAsync(stype, 0, (size_t)cap * 4, stream);
    hipMemsetAsync(seav, 0, (size_t)cap * 4, stream);

    int gE = (E + 255) / 256, gN = (N + 255) / 256;
    // bucket edges by relation (self-loops appended to bucket R-1)
    k_hist<<<gE, 256, 0, stream>>>(et, hist, E);
    k_scan<<<1, 1, 0, stream>>>(hist, start, curs, N);
    k_cnt_init<<<gN, 256, 0, stream>>>(cnt, N);
    k_scatter<<<gE, 256, 0, stream>>>(ei, et, ea, curs, ssrc, sdst, stype, seav, cnt, E);
    k_self<<<gN, 256, 0, stream>>>(curs, ssrc, sdst, stype, seav, N);

    int grid_e = cap / EB;
    int grid_f = N / 8;   // N = 50000, divisible by 8

    // layer 1 (h1 written into d_out; finish is row-local so in-place is safe)
    k_make_W<<<RREL * D * D / 256, 256, 0, stream>>>(att1, basis1, W);
    hipMemsetAsync(agg, 0, (size_t)N * D * 4, stream);
    k_edge_gemm<<<grid_e, 256, 0, stream>>>(x, W, ssrc, sdst, stype, seav, agg);
    k_finish<<<grid_f, 256, 0, stream>>>(x, agg, cnt, root1, bias1, g1, b1, out);

    // layer 2 (reads h1 from d_out, writes final into d_out)
    k_make_W<<<RREL * D * D / 256, 256, 0, stream>>>(att2, basis2, W);
    hipMemsetAsync(agg, 0, (size_t)N * D * 4, stream);
    k_edge_gemm<<<grid_e, 256, 0, stream>>>(out, W, ssrc, sdst, stype, seav, agg);
    k_finish<<<grid_f, 256, 0, stream>>>(out, agg, cnt, root2, bias2, g2, b2, out);
}

// Round 2
// 4315.859 us; speedup vs baseline: 3.9115x; 3.9115x over previous
//
#include <hip/hip_runtime.h>

#define D 256
#define RREL 16
#define BB 8
#define NB 8
#define LN_EPS 1e-5f

// ---------- CSR-by-destination construction ----------

__global__ void k_deg(const int* __restrict__ ei, int* __restrict__ deg, int E) {
    int e = blockIdx.x * 256 + threadIdx.x;
    if (e < E) atomicAdd(&deg[ei[E + e]], 1);
}

__global__ __launch_bounds__(256) void k_scan1(const int* __restrict__ deg,
                                               int* __restrict__ csum, int N) {
    __shared__ int sh[256];
    int n = blockIdx.x * 256 + threadIdx.x;
    sh[threadIdx.x] = (n < N) ? deg[n] : 0;
    __syncthreads();
    for (int off = 128; off > 0; off >>= 1) {
        if (threadIdx.x < off) sh[threadIdx.x] += sh[threadIdx.x + off];
        __syncthreads();
    }
    if (threadIdx.x == 0) csum[blockIdx.x] = sh[0];
}

__global__ void k_scan2(int* __restrict__ csum, int nch, int* __restrict__ rowptr, int N) {
    if (threadIdx.x == 0 && blockIdx.x == 0) {
        int s = 0;
        for (int i = 0; i < nch; ++i) { int c = csum[i]; csum[i] = s; s += c; }
        rowptr[N] = s;
    }
}

__global__ __launch_bounds__(256) void k_scan3(const int* __restrict__ deg,
                                               const int* __restrict__ csum,
                                               int* __restrict__ rowptr,
                                               int* __restrict__ cursor,
                                               float* __restrict__ cnt, int N) {
    __shared__ int sh[256];
    int tid = threadIdx.x;
    int n = blockIdx.x * 256 + tid;
    int v = (n < N) ? deg[n] : 0;
    sh[tid] = v;
    __syncthreads();
    for (int off = 1; off < 256; off <<= 1) {
        int t = (tid >= off) ? sh[tid - off] : 0;
        __syncthreads();
        sh[tid] += t;
        __syncthreads();
    }
    int excl = sh[tid] - v + csum[blockIdx.x];
    if (n < N) {
        rowptr[n] = excl;
        cursor[n] = excl;
        cnt[n] = (float)(v + 1);   // +1 self-loop
    }
}

__global__ void k_scatter(const int* __restrict__ ei, const int* __restrict__ et,
                          const float* __restrict__ ea, int* __restrict__ cursor,
                          int* __restrict__ esrc, int* __restrict__ eet,
                          float* __restrict__ eea, int E) {
    int e = blockIdx.x * 256 + threadIdx.x;
    if (e >= E) return;
    int dst = ei[E + e];
    int p = atomicAdd(&cursor[dst], 1);
    esrc[p] = ei[e];
    eet[p]  = et[e];
    eea[p]  = ea[e];
}

// ---------- main per-layer kernel ----------
// Per block: 8 dst nodes. Phase 1 (gather): G[k][b][:] = sum over incoming
// edges of ea*att[et,b]*x[src]  (+ self-loop att[R-1,b]*x[n]); slot b=8 holds
// cnt[n]*x[n] so the root GEMM rides the same contraction.
// Phase 2 (transform): agg[n] = sum_b G[n,b,:] @ basis[b]  (b=8 -> root).
__global__ __launch_bounds__(256) void k_gather(
    const float* __restrict__ x, const float* __restrict__ basis,
    const float* __restrict__ root, const float* __restrict__ att,
    const int* __restrict__ rowptr, const int* __restrict__ esrc,
    const int* __restrict__ eet, const float* __restrict__ eea,
    const float* __restrict__ cnt, float* __restrict__ agg) {
    __shared__ float Gs[NB][BB + 1][D];   // 72 KB
    __shared__ float att_s[RREL * BB];
    int tid = threadIdx.x;
    int row0 = blockIdx.x * NB;
    if (tid < RREL * BB) att_s[tid] = att[tid];
    __syncthreads();

    for (int k = 0; k < NB; ++k) {
        int n = row0 + k;
        float xv = x[(size_t)n * D + tid];
        float g[BB];
#pragma unroll
        for (int b = 0; b < BB; ++b) g[b] = att_s[(RREL - 1) * BB + b] * xv;  // self-loop
        Gs[k][BB][tid] = cnt[n] * xv;                                         // root slot
        int e0 = rowptr[n], e1 = rowptr[n + 1];
        for (int e = e0; e < e1; ++e) {
            int s = esrc[e];
            int r = eet[e];
            float w = eea[e];
            float xs = x[(size_t)s * D + tid];
#pragma unroll
            for (int b = 0; b < BB; ++b) g[b] += (w * att_s[r * BB + b]) * xs;
        }
#pragma unroll
        for (int b = 0; b < BB; ++b) Gs[k][b][tid] = g[b];
    }
    __syncthreads();

    // transform: thread = (rep 0..3) x (64 feature-cols of 4); rep handles 2 nodes
    int rep = tid >> 6;
    int f0 = (tid & 63) * 4;
    int k0 = rep * 2;
    float acc[2][4];
#pragma unroll
    for (int kk = 0; kk < 2; ++kk)
#pragma unroll
        for (int j = 0; j < 4; ++j) acc[kk][j] = 0.f;

    for (int b = 0; b < BB + 1; ++b) {
        const float* wp = (b < BB) ? (basis + (size_t)b * D * D) : root;
        for (int i = 0; i < D; i += 4) {
            float4 w0 = *(const float4*)&wp[(i + 0) * D + f0];
            float4 w1 = *(const float4*)&wp[(i + 1) * D + f0];
            float4 w2 = *(const float4*)&wp[(i + 2) * D + f0];
            float4 w3 = *(const float4*)&wp[(i + 3) * D + f0];
#pragma unroll
            for (int kk = 0; kk < 2; ++kk) {
                float4 gv = *(const float4*)&Gs[k0 + kk][b][i];
                acc[kk][0] += gv.x * w0.x + gv.y * w1.x + gv.z * w2.x + gv.w * w3.x;
                acc[kk][1] += gv.x * w0.y + gv.y * w1.y + gv.z * w2.y + gv.w * w3.y;
                acc[kk][2] += gv.x * w0.z + gv.y * w1.z + gv.z * w2.z + gv.w * w3.z;
                acc[kk][3] += gv.x * w0.w + gv.y * w1.w + gv.z * w2.w + gv.w * w3.w;
            }
        }
    }
#pragma unroll
    for (int kk = 0; kk < 2; ++kk)
        *(float4*)&agg[(size_t)(row0 + k0 + kk) * D + f0] = *(float4*)&acc[kk][0];
}

// out = relu(LN(hin + agg/cnt + bias)) -- 8 rows/block; in-place safe (row-local)
__global__ __launch_bounds__(256) void k_finish(
    const float* __restrict__ hin, const float* __restrict__ agg,
    const float* __restrict__ cnt, const float* __restrict__ bias,
    const float* __restrict__ g, const float* __restrict__ bln,
    float* __restrict__ hout) {
    __shared__ float Rs[8][D];
    __shared__ float mv[8][2];
    int tid = threadIdx.x;
    int row0 = blockIdx.x * 8;
    float bo = bias[tid];
#pragma unroll
    for (int k = 0; k < 8; ++k) {
        int n = row0 + k;
        Rs[k][tid] = hin[(size_t)n * D + tid] + agg[(size_t)n * D + tid] / cnt[n] + bo;
    }
    __syncthreads();

    int wv = tid >> 6, lane = tid & 63;
#pragma unroll
    for (int rr = 0; rr < 2; ++rr) {
        int row = wv * 2 + rr;
        float s = 0.f, sq = 0.f;
#pragma unroll
        for (int j = 0; j < 4; ++j) {
            float v = Rs[row][lane + j * 64];
            s += v;
            sq += v * v;
        }
#pragma unroll
        for (int off = 32; off >= 1; off >>= 1) {
            s += __shfl_xor(s, off, 64);
            sq += __shfl_xor(sq, off, 64);
        }
        if (lane == 0) {
            float mu = s * (1.f / D);
            float var = sq * (1.f / D) - mu * mu;
            mv[row][0] = mu;
            mv[row][1] = rsqrtf(var + LN_EPS);
        }
    }
    __syncthreads();

    float gg = g[tid], bb = bln[tid];
#pragma unroll
    for (int k = 0; k < 8; ++k) {
        float o = (Rs[k][tid] - mv[k][0]) * mv[k][1] * gg + bb;
        hout[(size_t)(row0 + k) * D + tid] = fmaxf(o, 0.f);
    }
}

extern "C" void kernel_launch(void* const* d_in, const int* in_sizes, int n_in,
                              void* d_out, int out_size, void* d_ws, size_t ws_size,
                              hipStream_t stream) {
    const float* x      = (const float*)d_in[0];
    const int*   ei     = (const int*)d_in[1];
    const int*   et     = (const int*)d_in[2];
    const float* ea     = (const float*)d_in[3];
    const float* basis1 = (const float*)d_in[4];
    const float* att1   = (const float*)d_in[5];
    const float* root1  = (const float*)d_in[6];
    const float* bias1  = (const float*)d_in[7];
    const float* g1     = (const float*)d_in[8];
    const float* b1     = (const float*)d_in[9];
    const float* basis2 = (const float*)d_in[10];
    const float* att2   = (const float*)d_in[11];
    const float* root2  = (const float*)d_in[12];
    const float* bias2  = (const float*)d_in[13];
    const float* g2     = (const float*)d_in[14];
    const float* b2     = (const float*)d_in[15];
    float* out = (float*)d_out;

    int N = in_sizes[0] / D;
    int E = in_sizes[2];
    int nch = (N + 255) / 256;

    char* p = (char*)d_ws;
    auto alloc = [&](size_t bytes) {
        char* q = p;
        p += (bytes + 255) & ~(size_t)255;
        return q;
    };
    float* agg    = (float*)alloc((size_t)N * D * 4);
    int*   deg    = (int*)  alloc((size_t)N * 4);
    int*   rowptr = (int*)  alloc((size_t)(N + 1) * 4);
    int*   cursor = (int*)  alloc((size_t)N * 4);
    float* cnt    = (float*)alloc((size_t)N * 4);
    int*   esrc   = (int*)  alloc((size_t)E * 4);
    int*   eet    = (int*)  alloc((size_t)E * 4);
    float* eea    = (float*)alloc((size_t)E * 4);
    int*   csum   = (int*)  alloc((size_t)nch * 4);

    hipMemsetAsync(deg, 0, (size_t)N * 4, stream);

    int gE = (E + 255) / 256;
    k_deg<<<gE, 256, 0, stream>>>(ei, deg, E);
    k_scan1<<<nch, 256, 0, stream>>>(deg, csum, N);
    k_scan2<<<1, 64, 0, stream>>>(csum, nch, rowptr, N);
    k_scan3<<<nch, 256, 0, stream>>>(deg, csum, rowptr, cursor, cnt, N);
    k_scatter<<<gE, 256, 0, stream>>>(ei, et, ea, cursor, esrc, eet, eea, E);

    int grid_g = N / NB;   // 50000 / 8 = 6250
    int grid_f = N / 8;

    // layer 1: h1 -> d_out
    k_gather<<<grid_g, 256, 0, stream>>>(x, basis1, root1, att1, rowptr, esrc, eet, eea, cnt, agg);
    k_finish<<<grid_f, 256, 0, stream>>>(x, agg, cnt, bias1, g1, b1, out);

    // layer 2: reads h1 from d_out, writes final in-place
    k_gather<<<grid_g, 256, 0, stream>>>(out, basis2, root2, att2, rowptr, esrc, eet, eea, cnt, agg);
    k_finish<<<grid_f, 256, 0, stream>>>(out, agg, cnt, bias2, g2, b2, out);
}

// Round 3
// 1003.165 us; speedup vs baseline: 16.8282x; 4.3022x over previous
//
#include <hip/hip_runtime.h>
#include <stdint.h>

#define D 256
#define RREL 16
#define BB 8
#define K9 2304          // (BB+1)*D
#define LN_EPS 1e-5f

typedef __attribute__((ext_vector_type(8))) short frag8;
typedef __attribute__((ext_vector_type(4))) float floatx4;

__device__ __forceinline__ unsigned short f2bf(float f) {
    union { float f; uint32_t u; } v; v.f = f;
    uint32_t r = (v.u + 0x7FFFu + ((v.u >> 16) & 1u)) >> 16;
    return (unsigned short)r;
}

__device__ __forceinline__ void gl2lds16(const unsigned short* g, char* l) {
    __builtin_amdgcn_global_load_lds((const __attribute__((address_space(1))) void*)g,
                                     (__attribute__((address_space(3))) void*)l, 16, 0, 0);
}

// ---------- CSR-by-destination ----------
__global__ void k_deg(const int* __restrict__ ei, int* __restrict__ deg, int E) {
    int e = blockIdx.x * 256 + threadIdx.x;
    if (e < E) atomicAdd(&deg[ei[E + e]], 1);
}

__global__ __launch_bounds__(256) void k_scan1(const int* __restrict__ deg,
                                               int* __restrict__ csum, int N) {
    __shared__ int sh[256];
    int n = blockIdx.x * 256 + threadIdx.x;
    sh[threadIdx.x] = (n < N) ? deg[n] : 0;
    __syncthreads();
    for (int off = 128; off > 0; off >>= 1) {
        if (threadIdx.x < off) sh[threadIdx.x] += sh[threadIdx.x + off];
        __syncthreads();
    }
    if (threadIdx.x == 0) csum[blockIdx.x] = sh[0];
}

__global__ void k_scan2(int* __restrict__ csum, int nch, int* __restrict__ rowptr, int N) {
    if (threadIdx.x == 0 && blockIdx.x == 0) {
        int s = 0;
        for (int i = 0; i < nch; ++i) { int c = csum[i]; csum[i] = s; s += c; }
        rowptr[N] = s;
    }
}

__global__ __launch_bounds__(256) void k_scan3(const int* __restrict__ deg,
                                               const int* __restrict__ csum,
                                               int* __restrict__ rowptr,
                                               int* __restrict__ cursor,
                                               float* __restrict__ cnt, int N) {
    __shared__ int sh[256];
    int tid = threadIdx.x;
    int n = blockIdx.x * 256 + tid;
    int v = (n < N) ? deg[n] : 0;
    sh[tid] = v;
    __syncthreads();
    for (int off = 1; off < 256; off <<= 1) {
        int t = (tid >= off) ? sh[tid - off] : 0;
        __syncthreads();
        sh[tid] += t;
        __syncthreads();
    }
    int excl = sh[tid] - v + csum[blockIdx.x];
    if (n < N) {
        rowptr[n] = excl;
        cursor[n] = excl;
        cnt[n] = (float)(v + 1);
    }
}

__global__ void k_scatter(const int* __restrict__ ei, const int* __restrict__ et,
                          const float* __restrict__ ea, int* __restrict__ cursor,
                          int* __restrict__ esr, float* __restrict__ eea, int E) {
    int e = blockIdx.x * 256 + threadIdx.x;
    if (e >= E) return;
    int dst = ei[E + e];
    int p = atomicAdd(&cursor[dst], 1);
    esr[p] = ei[e] | (et[e] << 24);   // src < 2^24, rel < 16
    eea[p] = ea[e];
}

// ---------- weight prep: Wt[o][k] bf16, k = b*256+i (b=8 -> root) ----------
__global__ __launch_bounds__(256) void k_prep_w(const float* __restrict__ basis,
                                                const float* __restrict__ root,
                                                unsigned short* __restrict__ Wt) {
    __shared__ float tile[64][65];
    int k0 = blockIdx.x * 64, o0 = blockIdx.y * 64;
    const float* src = (k0 < BB * D) ? (basis + (size_t)k0 * D)
                                     : (root + (size_t)(k0 - BB * D) * D);
    int tid = threadIdx.x;
#pragma unroll
    for (int t = 0; t < 16; ++t) {
        int idx = t * 256 + tid;
        int kk = idx >> 6, oo = idx & 63;
        tile[kk][oo] = src[(size_t)kk * D + o0 + oo];
    }
    __syncthreads();
#pragma unroll
    for (int t = 0; t < 16; ++t) {
        int idx = t * 256 + tid;
        int oo = idx >> 6, kk = idx & 63;
        Wt[(size_t)(o0 + oo) * K9 + k0 + kk] = f2bf(tile[kk][oo]);
    }
}

// ---------- gather: one wave per node, G[row][2304] bf16 ----------
__global__ __launch_bounds__(256) void k_gather(
    const float* __restrict__ x, const float* __restrict__ att,
    const int* __restrict__ rowptr, const int* __restrict__ esr,
    const float* __restrict__ eea, const float* __restrict__ cnt,
    unsigned short* __restrict__ G, int n0, int rows, int N) {
    __shared__ float att_s[RREL * BB];
    int tid = threadIdx.x;
    if (tid < RREL * BB) att_s[tid] = att[tid];
    __syncthreads();
    int wv = tid >> 6, lane = tid & 63;
    int rloc = blockIdx.x * 4 + wv;
    if (rloc >= rows) return;
    int n = n0 + rloc;
    unsigned short* gout = G + (size_t)rloc * K9 + lane * 4;
    if (n >= N) {   // pad row -> zeros
        ushort4 z = make_ushort4(0, 0, 0, 0);
#pragma unroll
        for (int b = 0; b <= BB; ++b) *(ushort4*)(gout + b * D) = z;
        return;
    }
    float4 xv4 = *(const float4*)&x[(size_t)n * D + lane * 4];
    float xv[4] = {xv4.x, xv4.y, xv4.z, xv4.w};
    float g[BB][4];
#pragma unroll
    for (int b = 0; b < BB; ++b) {
        float a = att_s[(RREL - 1) * BB + b];
#pragma unroll
        for (int j = 0; j < 4; ++j) g[b][j] = a * xv[j];
    }
    int e0 = rowptr[n], e1 = rowptr[n + 1];
    for (int e = e0; e < e1; ++e) {
        int pv = esr[e];
        int s = pv & 0xFFFFFF;
        int r = pv >> 24;
        float w = eea[e];
        float4 xs4 = *(const float4*)&x[(size_t)s * D + lane * 4];
        float xs[4] = {xs4.x, xs4.y, xs4.z, xs4.w};
#pragma unroll
        for (int b = 0; b < BB; ++b) {
            float coef = w * att_s[r * BB + b];
#pragma unroll
            for (int j = 0; j < 4; ++j) g[b][j] += coef * xs[j];
        }
    }
#pragma unroll
    for (int b = 0; b < BB; ++b) {
        ushort4 o = make_ushort4(f2bf(g[b][0]), f2bf(g[b][1]), f2bf(g[b][2]), f2bf(g[b][3]));
        *(ushort4*)(gout + b * D) = o;
    }
    float cn = cnt[n];
    ushort4 o = make_ushort4(f2bf(cn * xv[0]), f2bf(cn * xv[1]),
                             f2bf(cn * xv[2]), f2bf(cn * xv[3]));
    *(ushort4*)(gout + BB * D) = o;
}

// ---------- fused GEMM (64x256, K=2304, bf16 MFMA) + mean + residual + LN + ReLU ----------
__global__ __launch_bounds__(256, 2) void k_gemm(
    const unsigned short* __restrict__ G, const unsigned short* __restrict__ Wt,
    const float* __restrict__ hin, const float* __restrict__ cnt,
    const float* __restrict__ bias, const float* __restrict__ gln,
    const float* __restrict__ bln, float* __restrict__ hout, int n0, int N) {
    // union: staging As(8KB)+Bs(32KB) vs epilogue Cs 64*257*4
    __shared__ __align__(16) char smem[64 * 257 * 4];
    char* Asb = smem;
    char* Bsb = smem + 8192;
    float* Cs = (float*)smem;
    __shared__ float mu_s[64], rs_s[64];

    int tid = threadIdx.x;
    int wv = tid >> 6, lane = tid & 63;
    int quad = lane >> 4, l16 = lane & 15;
    int grow = blockIdx.x * 64;          // chunk-local row base
    int nb = n0 + grow;                  // global node base

    // staging address setup (XOR-swizzled 16B granules: slot = g ^ (row&7))
    const unsigned short* gA[2]; char* lA[2];
#pragma unroll
    for (int t = 0; t < 2; ++t) {
        int c = (wv * 2 + t) * 64 + lane;
        int arow = c >> 3, aslot = c & 7;
        gA[t] = G + (size_t)(grow + arow) * K9 + ((aslot ^ (arow & 7)) << 3);
        lA[t] = Asb + ((wv * 2 + t) << 10);
    }
    const unsigned short* gB[8]; char* lB[8];
#pragma unroll
    for (int t = 0; t < 8; ++t) {
        int c = (wv * 8 + t) * 64 + lane;
        int brow = c >> 3, bslot = c & 7;
        gB[t] = Wt + (size_t)brow * K9 + ((bslot ^ (brow & 7)) << 3);
        lB[t] = Bsb + ((wv * 8 + t) << 10);
    }

    floatx4 acc[4][4];
#pragma unroll
    for (int mf = 0; mf < 4; ++mf)
#pragma unroll
        for (int nf = 0; nf < 4; ++nf) acc[mf][nf] = (floatx4){0.f, 0.f, 0.f, 0.f};

    for (int it = 0; it < K9 / 64; ++it) {
        __syncthreads();
        int koff = it * 64;   // shorts
#pragma unroll
        for (int t = 0; t < 2; ++t) gl2lds16(gA[t] + koff, lA[t]);
#pragma unroll
        for (int t = 0; t < 8; ++t) gl2lds16(gB[t] + koff, lB[t]);
        __syncthreads();
#pragma unroll
        for (int kc = 0; kc < 2; ++kc) {
            int g = kc * 4 + quad;
            frag8 a[4], b[4];
#pragma unroll
            for (int mf = 0; mf < 4; ++mf) {
                int arow = mf * 16 + l16;
                a[mf] = *(const frag8*)(Asb + arow * 128 + ((g ^ (arow & 7)) << 4));
            }
#pragma unroll
            for (int nf = 0; nf < 4; ++nf) {
                int brow = wv * 64 + nf * 16 + l16;
                b[nf] = *(const frag8*)(Bsb + brow * 128 + ((g ^ (brow & 7)) << 4));
            }
#pragma unroll
            for (int mf = 0; mf < 4; ++mf)
#pragma unroll
                for (int nf = 0; nf < 4; ++nf)
                    acc[mf][nf] = __builtin_amdgcn_mfma_f32_16x16x32_bf16(
                        a[mf], b[nf], acc[mf][nf], 0, 0, 0);
        }
    }

    __syncthreads();   // all waves done with As/Bs; reuse as Cs
#pragma unroll
    for (int mf = 0; mf < 4; ++mf)
#pragma unroll
        for (int nf = 0; nf < 4; ++nf) {
            int col = wv * 64 + nf * 16 + l16;
#pragma unroll
            for (int r = 0; r < 4; ++r) {
                int row = mf * 16 + quad * 4 + r;
                Cs[row * 257 + col] = acc[mf][nf][r];
            }
        }
    __syncthreads();

    // residual + mean-div + bias
    float bo = bias[tid];
    for (int r = 0; r < 64; ++r) {
        int n = nb + r;
        if (n < N) {
            float inv = 1.0f / cnt[n];
            Cs[r * 257 + tid] = Cs[r * 257 + tid] * inv + hin[(size_t)n * D + tid] + bo;
        }
    }
    __syncthreads();

    // LN stats: 4 threads per row
    {
        int row = tid >> 2, q = tid & 3;
        float s = 0.f, sq = 0.f;
        for (int j = 0; j < 64; ++j) {
            float v = Cs[row * 257 + q * 64 + j];
            s += v; sq += v * v;
        }
        s += __shfl_xor(s, 1); sq += __shfl_xor(sq, 1);
        s += __shfl_xor(s, 2); sq += __shfl_xor(sq, 2);
        if (q == 0) {
            float mu = s * (1.f / D);
            mu_s[row] = mu;
            rs_s[row] = rsqrtf(sq * (1.f / D) - mu * mu + LN_EPS);
        }
    }
    __syncthreads();

    float gg = gln[tid], bb2 = bln[tid];
    for (int r = 0; r < 64; ++r) {
        int n = nb + r;
        if (n < N) {
            float o = (Cs[r * 257 + tid] - mu_s[r]) * rs_s[r] * gg + bb2;
            hout[(size_t)n * D + tid] = fmaxf(o, 0.f);
        }
    }
}

extern "C" void kernel_launch(void* const* d_in, const int* in_sizes, int n_in,
                              void* d_out, int out_size, void* d_ws, size_t ws_size,
                              hipStream_t stream) {
    const float* x      = (const float*)d_in[0];
    const int*   ei     = (const int*)d_in[1];
    const int*   et     = (const int*)d_in[2];
    const float* ea     = (const float*)d_in[3];
    const float* basis1 = (const float*)d_in[4];
    const float* att1   = (const float*)d_in[5];
    const float* root1  = (const float*)d_in[6];
    const float* bias1  = (const float*)d_in[7];
    const float* g1     = (const float*)d_in[8];
    const float* b1     = (const float*)d_in[9];
    const float* basis2 = (const float*)d_in[10];
    const float* att2   = (const float*)d_in[11];
    const float* root2  = (const float*)d_in[12];
    const float* bias2  = (const float*)d_in[13];
    const float* g2     = (const float*)d_in[14];
    const float* b2     = (const float*)d_in[15];
    float* out = (float*)d_out;

    int N = in_sizes[0] / D;
    int E = in_sizes[2];
    int nch = (N + 255) / 256;
    int Mp = ((N + 63) / 64) * 64;
    int T = Mp / 64;

    char* p = (char*)d_ws;
    size_t used = 0;
    auto alloc = [&](size_t bytes) {
        char* q = p;
        size_t a = (bytes + 255) & ~(size_t)255;
        p += a; used += a;
        return q;
    };
    float*          h1     = (float*)alloc((size_t)N * D * 4);
    unsigned short* Wt     = (unsigned short*)alloc((size_t)K9 * D * 2);
    int*            deg    = (int*)alloc((size_t)N * 4);
    int*            rowptr = (int*)alloc((size_t)(N + 1) * 4);
    int*            cursor = (int*)alloc((size_t)N * 4);
    float*          cnt    = (float*)alloc((size_t)N * 4);
    int*            esr    = (int*)alloc((size_t)E * 4);
    float*          eea    = (float*)alloc((size_t)E * 4);
    int*            csum   = (int*)alloc((size_t)nch * 4);
    // G takes the rest; chunk rows if workspace is tight
    size_t remain = (ws_size > used + 256) ? (ws_size - used - 256) : 0;
    size_t tile_bytes = (size_t)64 * K9 * 2;
    int ct = (int)(remain / tile_bytes);
    if (ct < 1) ct = 1;
    if (ct > T) ct = T;
    unsigned short* G = (unsigned short*)alloc((size_t)ct * tile_bytes);

    hipMemsetAsync(deg, 0, (size_t)N * 4, stream);
    int gE = (E + 255) / 256;
    k_deg<<<gE, 256, 0, stream>>>(ei, deg, E);
    k_scan1<<<nch, 256, 0, stream>>>(deg, csum, N);
    k_scan2<<<1, 64, 0, stream>>>(csum, nch, rowptr, N);
    k_scan3<<<nch, 256, 0, stream>>>(deg, csum, rowptr, cursor, cnt, N);
    k_scatter<<<gE, 256, 0, stream>>>(ei, et, ea, cursor, esr, eea, E);

    const float* bas[2]  = {basis1, basis2};
    const float* attp[2] = {att1, att2};
    const float* rt[2]   = {root1, root2};
    const float* bi[2]   = {bias1, bias2};
    const float* lg[2]   = {g1, g2};
    const float* lb[2]   = {b1, b2};
    const float* hin[2]  = {x, h1};
    float*       hot[2]  = {h1, out};

    for (int L = 0; L < 2; ++L) {
        k_prep_w<<<dim3(K9 / 64, D / 64), 256, 0, stream>>>(bas[L], rt[L], Wt);
        for (int c0 = 0; c0 < T; c0 += ct) {
            int tiles = (T - c0 < ct) ? (T - c0) : ct;
            int rows = tiles * 64;
            int n0 = c0 * 64;
            k_gather<<<rows / 4, 256, 0, stream>>>(hin[L], attp[L], rowptr, esr, eea,
                                                   cnt, G, n0, rows, N);
            k_gemm<<<tiles, 256, 0, stream>>>(G, Wt, hin[L], cnt, bi[L], lg[L], lb[L],
                                              hot[L], n0, N);
        }
    }
}

// Round 4
// 809.082 us; speedup vs baseline: 20.8650x; 1.2399x over previous
//
#include <hip/hip_runtime.h>
#include <stdint.h>

#define D 256
#define RREL 16
#define BB 8
#define K9 2304          // (BB+1)*D
#define LN_EPS 1e-5f

typedef __attribute__((ext_vector_type(8))) short frag8;
typedef __attribute__((ext_vector_type(4))) float floatx4;

__device__ __forceinline__ unsigned short f2bf(float f) {
    union { float f; uint32_t u; } v; v.f = f;
    uint32_t r = (v.u + 0x7FFFu + ((v.u >> 16) & 1u)) >> 16;
    return (unsigned short)r;
}
__device__ __forceinline__ float bf2f(unsigned short u) {
    union { uint32_t u; float f; } v; v.u = (uint32_t)u << 16;
    return v.f;
}

__device__ __forceinline__ void gl2lds16(const unsigned short* g, char* l) {
    __builtin_amdgcn_global_load_lds((const __attribute__((address_space(1))) void*)g,
                                     (__attribute__((address_space(3))) void*)l, 16, 0, 0);
}

// ---------- fp32 -> bf16 bulk convert ----------
__global__ __launch_bounds__(256) void k_cvt(const float* __restrict__ src,
                                             unsigned short* __restrict__ dst, int n4) {
    int i = blockIdx.x * 256 + threadIdx.x;
    if (i >= n4) return;
    float4 v = ((const float4*)src)[i];
    ushort4 o = make_ushort4(f2bf(v.x), f2bf(v.y), f2bf(v.z), f2bf(v.w));
    ((ushort4*)dst)[i] = o;
}

// ---------- CSR-by-destination ----------
__global__ void k_deg(const int* __restrict__ ei, int* __restrict__ deg, int E) {
    int e = blockIdx.x * 256 + threadIdx.x;
    if (e < E) atomicAdd(&deg[ei[E + e]], 1);
}

__global__ __launch_bounds__(256) void k_scan1(const int* __restrict__ deg,
                                               int* __restrict__ csum, int N) {
    __shared__ int sh[256];
    int n = blockIdx.x * 256 + threadIdx.x;
    sh[threadIdx.x] = (n < N) ? deg[n] : 0;
    __syncthreads();
    for (int off = 128; off > 0; off >>= 1) {
        if (threadIdx.x < off) sh[threadIdx.x] += sh[threadIdx.x + off];
        __syncthreads();
    }
    if (threadIdx.x == 0) csum[blockIdx.x] = sh[0];
}

__global__ void k_scan2(int* __restrict__ csum, int nch, int* __restrict__ rowptr, int N) {
    if (threadIdx.x == 0 && blockIdx.x == 0) {
        int s = 0;
        for (int i = 0; i < nch; ++i) { int c = csum[i]; csum[i] = s; s += c; }
        rowptr[N] = s;
    }
}

__global__ __launch_bounds__(256) void k_scan3(const int* __restrict__ deg,
                                               const int* __restrict__ csum,
                                               int* __restrict__ rowptr,
                                               int* __restrict__ cursor,
                                               float* __restrict__ cnt, int N) {
    __shared__ int sh[256];
    int tid = threadIdx.x;
    int n = blockIdx.x * 256 + tid;
    int v = (n < N) ? deg[n] : 0;
    sh[tid] = v;
    __syncthreads();
    for (int off = 1; off < 256; off <<= 1) {
        int t = (tid >= off) ? sh[tid - off] : 0;
        __syncthreads();
        sh[tid] += t;
        __syncthreads();
    }
    int excl = sh[tid] - v + csum[blockIdx.x];
    if (n < N) {
        rowptr[n] = excl;
        cursor[n] = excl;
        cnt[n] = (float)(v + 1);
    }
}

__global__ void k_scatter(const int* __restrict__ ei, const int* __restrict__ et,
                          const float* __restrict__ ea, int* __restrict__ cursor,
                          int2* __restrict__ ep, int E) {
    int e = blockIdx.x * 256 + threadIdx.x;
    if (e >= E) return;
    int dst = ei[E + e];
    int p = atomicAdd(&cursor[dst], 1);
    ep[p] = make_int2(ei[e] | (et[e] << 24), __float_as_int(ea[e]));
}

// ---------- weight prep: Wt[o][k] bf16, k = b*256+i (b=8 -> root) ----------
__global__ __launch_bounds__(256) void k_prep_w(const float* __restrict__ basis,
                                                const float* __restrict__ root,
                                                unsigned short* __restrict__ Wt) {
    __shared__ float tile[64][65];
    int k0 = blockIdx.x * 64, o0 = blockIdx.y * 64;
    const float* src = (k0 < BB * D) ? (basis + (size_t)k0 * D)
                                     : (root + (size_t)(k0 - BB * D) * D);
    int tid = threadIdx.x;
#pragma unroll
    for (int t = 0; t < 16; ++t) {
        int idx = t * 256 + tid;
        int kk = idx >> 6, oo = idx & 63;
        tile[kk][oo] = src[(size_t)kk * D + o0 + oo];
    }
    __syncthreads();
#pragma unroll
    for (int t = 0; t < 16; ++t) {
        int idx = t * 256 + tid;
        int oo = idx >> 6, kk = idx & 63;
        Wt[(size_t)(o0 + oo) * K9 + k0 + kk] = f2bf(tile[kk][oo]);
    }
}

// ---------- gather: one wave per node, reads bf16 x, writes G[row][2304] bf16 ----------
__global__ __launch_bounds__(256) void k_gather(
    const unsigned short* __restrict__ xb, const float* __restrict__ att,
    const int* __restrict__ rowptr, const int2* __restrict__ ep,
    const float* __restrict__ cnt, unsigned short* __restrict__ G,
    int n0, int rows, int N) {
    __shared__ float att_s[RREL * BB];
    int tid = threadIdx.x;
    if (tid < RREL * BB) att_s[tid] = att[tid];
    __syncthreads();
    int wv = tid >> 6, lane = tid & 63;
    int rloc = blockIdx.x * 4 + wv;
    if (rloc >= rows) return;
    int n = n0 + rloc;
    unsigned short* gout = G + (size_t)rloc * K9 + lane * 4;
    if (n >= N) {
        ushort4 z = make_ushort4(0, 0, 0, 0);
#pragma unroll
        for (int b = 0; b <= BB; ++b) *(ushort4*)(gout + b * D) = z;
        return;
    }
    ushort4 xu = *(const ushort4*)&xb[(size_t)n * D + lane * 4];
    float xv[4] = {bf2f(xu.x), bf2f(xu.y), bf2f(xu.z), bf2f(xu.w)};
    float g[BB][4];
#pragma unroll
    for (int b = 0; b < BB; ++b) {
        float a = att_s[(RREL - 1) * BB + b];
#pragma unroll
        for (int j = 0; j < 4; ++j) g[b][j] = a * xv[j];
    }
    int e0 = rowptr[n], e1 = rowptr[n + 1];
    int e = e0;
    for (; e + 2 <= e1; e += 2) {           // 2 edges/iter -> 2 outstanding row loads
        int2 pa = ep[e], pb = ep[e + 1];
        ushort4 ua = *(const ushort4*)&xb[(size_t)(pa.x & 0xFFFFFF) * D + lane * 4];
        ushort4 ub = *(const ushort4*)&xb[(size_t)(pb.x & 0xFFFFFF) * D + lane * 4];
        float wa = __int_as_float(pa.y), wb = __int_as_float(pb.y);
        int ra = (unsigned)pa.x >> 24, rb = (unsigned)pb.x >> 24;
        float xa[4] = {bf2f(ua.x), bf2f(ua.y), bf2f(ua.z), bf2f(ua.w)};
        float xc[4] = {bf2f(ub.x), bf2f(ub.y), bf2f(ub.z), bf2f(ub.w)};
#pragma unroll
        for (int b = 0; b < BB; ++b) {
            float ca = wa * att_s[ra * BB + b];
            float cb = wb * att_s[rb * BB + b];
#pragma unroll
            for (int j = 0; j < 4; ++j) g[b][j] += ca * xa[j] + cb * xc[j];
        }
    }
    if (e < e1) {
        int2 pa = ep[e];
        ushort4 ua = *(const ushort4*)&xb[(size_t)(pa.x & 0xFFFFFF) * D + lane * 4];
        float wa = __int_as_float(pa.y);
        int ra = (unsigned)pa.x >> 24;
        float xa[4] = {bf2f(ua.x), bf2f(ua.y), bf2f(ua.z), bf2f(ua.w)};
#pragma unroll
        for (int b = 0; b < BB; ++b) {
            float ca = wa * att_s[ra * BB + b];
#pragma unroll
            for (int j = 0; j < 4; ++j) g[b][j] += ca * xa[j];
        }
    }
#pragma unroll
    for (int b = 0; b < BB; ++b) {
        ushort4 o = make_ushort4(f2bf(g[b][0]), f2bf(g[b][1]), f2bf(g[b][2]), f2bf(g[b][3]));
        *(ushort4*)(gout + b * D) = o;
    }
    float cn = cnt[n];
    ushort4 o = make_ushort4(f2bf(cn * xv[0]), f2bf(cn * xv[1]),
                             f2bf(cn * xv[2]), f2bf(cn * xv[3]));
    *(ushort4*)(gout + BB * D) = o;
}

// ---------- fused GEMM (64x256, K=2304, bf16 MFMA) + mean + residual + LN + ReLU ----------
// Register epilogue: LDS = 40960 B exactly -> 4 blocks/CU; launch_bounds(256,4) caps VGPR<=128.
__global__ __launch_bounds__(256, 4) void k_gemm(
    const unsigned short* __restrict__ G, const unsigned short* __restrict__ Wt,
    const float* __restrict__ hin, const float* __restrict__ cnt,
    const float* __restrict__ bias, const float* __restrict__ gln,
    const float* __restrict__ bln, float* __restrict__ hout,
    unsigned short* __restrict__ houtb, int n0, int N) {
    __shared__ __align__(16) char smem[40960];
    char* Asb = smem;
    char* Bsb = smem + 8192;
    // post-loop aliases (A-staging buffer is idle during the epilogue)
    float* ps   = (float*)smem;          // [64][4] row-sum partials per wave
    float* pq   = ps + 256;              // [64][4]
    float* mu_s = ps + 512;              // [64]
    float* rs_s = ps + 576;              // [64]

    int tid = threadIdx.x;
    int wv = tid >> 6, lane = tid & 63;
    int quad = lane >> 4, l16 = lane & 15;
    int grow = blockIdx.x * 64;          // chunk-local row base
    int nb = n0 + grow;                  // global node base

    // staging addresses (XOR-swizzled 16B granules: slot = g ^ (row&7))
    const unsigned short* gA[2]; char* lA[2];
#pragma unroll
    for (int t = 0; t < 2; ++t) {
        int c = (wv * 2 + t) * 64 + lane;
        int arow = c >> 3, aslot = c & 7;
        gA[t] = G + (size_t)(grow + arow) * K9 + ((aslot ^ (arow & 7)) << 3);
        lA[t] = Asb + ((wv * 2 + t) << 10);
    }
    const unsigned short* gB[8]; char* lB[8];
#pragma unroll
    for (int t = 0; t < 8; ++t) {
        int c = (wv * 8 + t) * 64 + lane;
        int brow = c >> 3, bslot = c & 7;
        gB[t] = Wt + (size_t)brow * K9 + ((bslot ^ (brow & 7)) << 3);
        lB[t] = Bsb + ((wv * 8 + t) << 10);
    }

    floatx4 acc[4][4];
#pragma unroll
    for (int mf = 0; mf < 4; ++mf)
#pragma unroll
        for (int nf = 0; nf < 4; ++nf) acc[mf][nf] = (floatx4){0.f, 0.f, 0.f, 0.f};

    for (int it = 0; it < K9 / 64; ++it) {
        __syncthreads();
        int koff = it * 64;
#pragma unroll
        for (int t = 0; t < 2; ++t) gl2lds16(gA[t] + koff, lA[t]);
#pragma unroll
        for (int t = 0; t < 8; ++t) gl2lds16(gB[t] + koff, lB[t]);
        __syncthreads();
#pragma unroll
        for (int kc = 0; kc < 2; ++kc) {
            int g = kc * 4 + quad;
            frag8 a[4], b[4];
#pragma unroll
            for (int mf = 0; mf < 4; ++mf) {
                int arow = mf * 16 + l16;
                a[mf] = *(const frag8*)(Asb + arow * 128 + ((g ^ (arow & 7)) << 4));
            }
#pragma unroll
            for (int nf = 0; nf < 4; ++nf) {
                int brow = wv * 64 + nf * 16 + l16;
                b[nf] = *(const frag8*)(Bsb + brow * 128 + ((g ^ (brow & 7)) << 4));
            }
#pragma unroll
            for (int mf = 0; mf < 4; ++mf)
#pragma unroll
                for (int nf = 0; nf < 4; ++nf)
                    acc[mf][nf] = __builtin_amdgcn_mfma_f32_16x16x32_bf16(
                        a[mf], b[nf], acc[mf][nf], 0, 0, 0);
        }
    }
    __syncthreads();   // all ds_reads done; A-staging region reusable for LN partials

    // ---- pass 1: val = acc/cnt + residual + bias; wave-local LN partials ----
    int col[4]; float bic[4];
#pragma unroll
    for (int nf = 0; nf < 4; ++nf) {
        col[nf] = wv * 64 + nf * 16 + l16;
        bic[nf] = bias[col[nf]];
    }
#pragma unroll
    for (int mf = 0; mf < 4; ++mf) {
#pragma unroll
        for (int r = 0; r < 4; ++r) {
            int row = mf * 16 + quad * 4 + r;
            int n = nb + row;
            float s = 0.f, sq = 0.f;
            if (n < N) {
                float inv = 1.0f / cnt[n];
                const float* hp = hin + (size_t)n * D;
#pragma unroll
                for (int nf = 0; nf < 4; ++nf) {
                    float v = acc[mf][nf][r] * inv + hp[col[nf]] + bic[nf];
                    acc[mf][nf][r] = v;
                    s += v; sq += v * v;
                }
            }
            s += __shfl_xor(s, 1); sq += __shfl_xor(sq, 1);
            s += __shfl_xor(s, 2); sq += __shfl_xor(sq, 2);
            s += __shfl_xor(s, 4); sq += __shfl_xor(sq, 4);
            s += __shfl_xor(s, 8); sq += __shfl_xor(sq, 8);
            if (l16 == 0) {
                ps[row * 4 + wv] = s;
                pq[row * 4 + wv] = sq;
            }
        }
    }
    __syncthreads();
    if (tid < 64) {
        float s  = ps[tid * 4] + ps[tid * 4 + 1] + ps[tid * 4 + 2] + ps[tid * 4 + 3];
        float sq = pq[tid * 4] + pq[tid * 4 + 1] + pq[tid * 4 + 2] + pq[tid * 4 + 3];
        float mu = s * (1.f / D);
        mu_s[tid] = mu;
        rs_s[tid] = rsqrtf(sq * (1.f / D) - mu * mu + LN_EPS);
    }
    __syncthreads();

    // ---- pass 2: normalize + ReLU + store (fp32, optional bf16 copy) ----
    float gc[4], bc[4];
#pragma unroll
    for (int nf = 0; nf < 4; ++nf) {
        gc[nf] = gln[col[nf]];
        bc[nf] = bln[col[nf]];
    }
#pragma unroll
    for (int mf = 0; mf < 4; ++mf) {
#pragma unroll
        for (int r = 0; r < 4; ++r) {
            int row = mf * 16 + quad * 4 + r;
            int n = nb + row;
            if (n >= N) continue;
            float mu = mu_s[row], rs = rs_s[row];
            float* op = hout + (size_t)n * D;
#pragma unroll
            for (int nf = 0; nf < 4; ++nf) {
                float o = fmaxf((acc[mf][nf][r] - mu) * rs * gc[nf] + bc[nf], 0.f);
                op[col[nf]] = o;
                if (houtb) houtb[(size_t)n * D + col[nf]] = f2bf(o);
            }
        }
    }
}

extern "C" void kernel_launch(void* const* d_in, const int* in_sizes, int n_in,
                              void* d_out, int out_size, void* d_ws, size_t ws_size,
                              hipStream_t stream) {
    const float* x      = (const float*)d_in[0];
    const int*   ei     = (const int*)d_in[1];
    const int*   et     = (const int*)d_in[2];
    const float* ea     = (const float*)d_in[3];
    const float* basis1 = (const float*)d_in[4];
    const float* att1   = (const float*)d_in[5];
    const float* root1  = (const float*)d_in[6];
    const float* bias1  = (const float*)d_in[7];
    const float* g1     = (const float*)d_in[8];
    const float* b1     = (const float*)d_in[9];
    const float* basis2 = (const float*)d_in[10];
    const float* att2   = (const float*)d_in[11];
    const float* root2  = (const float*)d_in[12];
    const float* bias2  = (const float*)d_in[13];
    const float* g2     = (const float*)d_in[14];
    const float* b2     = (const float*)d_in[15];
    float* out = (float*)d_out;

    int N = in_sizes[0] / D;
    int E = in_sizes[2];
    int nch = (N + 255) / 256;
    int Mp = ((N + 63) / 64) * 64;
    int T = Mp / 64;

    char* p = (char*)d_ws;
    size_t used = 0;
    auto alloc = [&](size_t bytes) {
        char* q = p;
        size_t a = (bytes + 255) & ~(size_t)255;
        p += a; used += a;
        return q;
    };
    float*          h1     = (float*)alloc((size_t)N * D * 4);
    unsigned short* xb     = (unsigned short*)alloc((size_t)N * D * 2);
    unsigned short* h1b    = (unsigned short*)alloc((size_t)N * D * 2);
    unsigned short* Wt     = (unsigned short*)alloc((size_t)K9 * D * 2);
    int*            deg    = (int*)alloc((size_t)N * 4);
    int*            rowptr = (int*)alloc((size_t)(N + 1) * 4);
    int*            cursor = (int*)alloc((size_t)N * 4);
    float*          cnt    = (float*)alloc((size_t)N * 4);
    int2*           ep     = (int2*)alloc((size_t)E * 8);
    int*            csum   = (int*)alloc((size_t)nch * 4);
    size_t remain = (ws_size > used + 256) ? (ws_size - used - 256) : 0;
    size_t tile_bytes = (size_t)64 * K9 * 2;
    int ct = (int)(remain / tile_bytes);
    if (ct < 1) ct = 1;
    if (ct > T) ct = T;
    unsigned short* G = (unsigned short*)alloc((size_t)ct * tile_bytes);

    hipMemsetAsync(deg, 0, (size_t)N * 4, stream);
    int gE = (E + 255) / 256;
    k_deg<<<gE, 256, 0, stream>>>(ei, deg, E);
    k_scan1<<<nch, 256, 0, stream>>>(deg, csum, N);
    k_scan2<<<1, 64, 0, stream>>>(csum, nch, rowptr, N);
    k_scan3<<<nch, 256, 0, stream>>>(deg, csum, rowptr, cursor, cnt, N);
    k_scatter<<<gE, 256, 0, stream>>>(ei, et, ea, cursor, ep, E);
    k_cvt<<<(N * D / 4 + 255) / 256, 256, 0, stream>>>(x, xb, N * D / 4);

    const float* bas[2]  = {basis1, basis2};
    const float* attp[2] = {att1, att2};
    const float* rt[2]   = {root1, root2};
    const float* bi[2]   = {bias1, bias2};
    const float* lg[2]   = {g1, g2};
    const float* lb[2]   = {b1, b2};
    const unsigned short* gin[2] = {xb, h1b};
    const float* hres[2] = {x, h1};
    float*          hof[2] = {h1, out};
    unsigned short* hob[2] = {h1b, nullptr};

    for (int L = 0; L < 2; ++L) {
        k_prep_w<<<dim3(K9 / 64, D / 64), 256, 0, stream>>>(bas[L], rt[L], Wt);
        for (int c0 = 0; c0 < T; c0 += ct) {
            int tiles = (T - c0 < ct) ? (T - c0) : ct;
            int rows = tiles * 64;
            int n0 = c0 * 64;
            k_gather<<<rows / 4, 256, 0, stream>>>(gin[L], attp[L], rowptr, ep,
                                                   cnt, G, n0, rows, N);
            k_gemm<<<tiles, 256, 0, stream>>>(G, Wt, hres[L], cnt, bi[L], lg[L], lb[L],
                                              hof[L], hob[L], n0, N);
        }
    }
}